// Round 1
// baseline (43.977 us; speedup 1.0000x reference)
//
#include <hip/hip_runtime.h>
#include <math.h>

// Problem constants (B=256, S=512, J=32, D=3)
constexpr int NGROUPS = 256 * 512 * 32;   // 4,194,304 (b,s,j) groups
constexpr int NQUAD   = NGROUPS / 4;      // 4 groups per thread
constexpr int BLOCK   = 256;
constexpr int GRID    = 2048;             // grid-stride, 2 iters/thread

#define LOG_2PI 1.8378770664093453f

__global__ __launch_bounds__(BLOCK) void nll_main(
    const float* __restrict__ yt,
    const float* __restrict__ yp,
    const float* __restrict__ Lm,
    float* __restrict__ partial)
{
    const float4* yt4 = reinterpret_cast<const float4*>(yt);
    const float4* yp4 = reinterpret_cast<const float4*>(yp);
    const float4* L4  = reinterpret_cast<const float4*>(Lm);

    float acc = 0.0f;
    const int stride = gridDim.x * blockDim.x;
    for (int q = blockIdx.x * blockDim.x + threadIdx.x; q < NQUAD; q += stride) {
        // 4 groups: d = y_true - y_pred  (12 floats = 3 float4)
        float d[12];
        float l[36];
        #pragma unroll
        for (int i = 0; i < 3; ++i) {
            float4 a = yt4[q * 3 + i];
            float4 b = yp4[q * 3 + i];
            d[i * 4 + 0] = a.x - b.x;
            d[i * 4 + 1] = a.y - b.y;
            d[i * 4 + 2] = a.z - b.z;
            d[i * 4 + 3] = a.w - b.w;
        }
        // 4 groups of 3x3 L (36 floats = 9 float4)
        #pragma unroll
        for (int i = 0; i < 9; ++i) {
            float4 v = L4[q * 9 + i];
            l[i * 4 + 0] = v.x;
            l[i * 4 + 1] = v.y;
            l[i * 4 + 2] = v.z;
            l[i * 4 + 3] = v.w;
        }
        #pragma unroll
        for (int g = 0; g < 4; ++g) {
            // row-major 3x3: L[0][0]=0, L[1][0]=3, L[1][1]=4, L[2][0]=6, L[2][1]=7, L[2][2]=8
            float L00 = l[g * 9 + 0];
            float L10 = l[g * 9 + 3];
            float L11 = l[g * 9 + 4];
            float L20 = l[g * 9 + 6];
            float L21 = l[g * 9 + 7];
            float L22 = l[g * 9 + 8];
            float d0 = d[g * 3 + 0];
            float d1 = d[g * 3 + 1];
            float d2 = d[g * 3 + 2];

            float x0 = d0 / L00;
            float x1 = (d1 - L10 * x0) / L11;
            float x2 = (d2 - L20 * x0 - L21 * x1) / L22;
            float maha   = x0 * x0 + x1 * x1 + x2 * x2;
            float logdet = 2.0f * (__logf(L00) + __logf(L11) + __logf(L22));
            acc += 0.5f * (maha + logdet + 3.0f * LOG_2PI);
        }
    }

    // wave (64-lane) shuffle reduce
    #pragma unroll
    for (int off = 32; off > 0; off >>= 1) acc += __shfl_down(acc, off, 64);

    __shared__ float sdata[BLOCK / 64];
    const int lane = threadIdx.x & 63;
    const int wid  = threadIdx.x >> 6;
    if (lane == 0) sdata[wid] = acc;
    __syncthreads();
    if (threadIdx.x == 0) {
        float s = 0.0f;
        #pragma unroll
        for (int w = 0; w < BLOCK / 64; ++w) s += sdata[w];
        partial[blockIdx.x] = s;
    }
}

__global__ __launch_bounds__(256) void nll_reduce(
    const float* __restrict__ partial, float* __restrict__ out)
{
    float acc = 0.0f;
    for (int i = threadIdx.x; i < GRID; i += 256) acc += partial[i];

    #pragma unroll
    for (int off = 32; off > 0; off >>= 1) acc += __shfl_down(acc, off, 64);

    __shared__ float sdata[4];
    const int lane = threadIdx.x & 63;
    const int wid  = threadIdx.x >> 6;
    if (lane == 0) sdata[wid] = acc;
    __syncthreads();
    if (threadIdx.x == 0) {
        out[0] = (sdata[0] + sdata[1] + sdata[2] + sdata[3]) *
                 (1.0f / (float)NGROUPS);
    }
}

extern "C" void kernel_launch(void* const* d_in, const int* in_sizes, int n_in,
                              void* d_out, int out_size, void* d_ws, size_t ws_size,
                              hipStream_t stream)
{
    const float* yt = (const float*)d_in[0];  // y_true        (B,S,J,D)
    const float* yp = (const float*)d_in[1];  // y_pred_mean   (B,S,J,D)
    const float* Lm = (const float*)d_in[2];  // pred_cholesky (B,S,J,D,D)
    float* out      = (float*)d_out;          // scalar mean
    float* partial  = (float*)d_ws;           // GRID floats of scratch

    nll_main<<<GRID, BLOCK, 0, stream>>>(yt, yp, Lm, partial);
    nll_reduce<<<1, 256, 0, stream>>>(partial, out);
}